// Round 1
// baseline (162.452 us; speedup 1.0000x reference)
//
#include <hip/hip_runtime.h>
#include <hip/hip_bf16.h>

// Encoder: neigh_feats = mean(raw[idx], axis=1); x = nf @ W; BN(train); LeakyReLU(0.01)
// Inputs (setup_inputs order):
//   d_in[0] raw_features [100000,128] f32
//   d_in[1] weight       [128,128]    f32
//   d_in[2] gamma        [128]        f32
//   d_in[3] beta         [128]        f32
//   d_in[4] neigh_idx    [50000,16]   int32 (jax int64 w/o x64 -> int32; harness: integer -> const int*)
// Output: [50000,128] f32
//
// Phase A: gather+mean -> bf16 -> MFMA 16x16x32 GEMM vs W^T(bf16, LDS) -> x to d_out,
//          block-reduced per-feature sum/sumsq atomics into d_ws[0:256].
// Phase B: scale/shift from stats, normalize d_out in place + LeakyReLU.

#define NTOTAL 100000
#define FEAT   128
#define NB     50000
#define KNEI   16
#define NTILES (NB / 16)   // 3125 exact

typedef float f32x4 __attribute__((ext_vector_type(4)));
typedef short bf16x8 __attribute__((ext_vector_type(8)));

__device__ __forceinline__ unsigned short f2bf(float f) {
    union { float f; unsigned u; } v; v.f = f;
    unsigned r = v.u + 0x7FFF + ((v.u >> 16) & 1);   // round-to-nearest-even
    return (unsigned short)(r >> 16);
}

// W^T in LDS, bf16, row stride 136 (pad 8 -> keeps 16B alignment, breaks pow2 banks)
#define WT_LD 136
#define A_LD  136

__global__ __launch_bounds__(256, 4) void enc_gemm(
    const float* __restrict__ raw, const float* __restrict__ W,
    const int* __restrict__ idx, float* __restrict__ out,
    float* __restrict__ gstats)
{
    __shared__ unsigned short sWt[128 * WT_LD];  // 34816 B
    __shared__ unsigned short sA[16 * A_LD];     //  4352 B
    __shared__ int sidx[256];                    //  1024 B

    const int t = threadIdx.x;

    // Stage W^T as bf16: sWt[n][f] = bf16(W[f][n])
    #pragma unroll 4
    for (int i = 0; i < 64; ++i) {
        int e = t + i * 256;
        int f = e >> 7, n = e & 127;
        sWt[n * WT_LD + f] = f2bf(W[e]);
    }

    const int lane = t & 63;
    const int wv = t >> 6;        // wave 0..3 -> n-chunk of 32
    const int ln = lane & 15;
    const int qd = lane >> 4;     // quad 0..3
    const int c = t & 31;         // float4 chunk within a 128-f row
    const int g = t >> 5;         // row-pair group 0..7

    float s1a = 0.f, s2a = 0.f, s1b = 0.f, s2b = 0.f;
    const float4* raw4 = (const float4*)raw;

    for (int tile = blockIdx.x; tile < NTILES; tile += gridDim.x) {
        const int i0 = tile * 16;
        __syncthreads();                       // protect sidx/sA from prior iter (also fences sWt on iter 0)
        sidx[t] = idx[i0 * KNEI + t];          // 256 ints, coalesced
        __syncthreads();

        // Gather + mean: thread handles rows g*2, g*2+1, float4-chunk c.
        // A wave (g spans 2 values) reads 2 full 512B neighbor rows per instruction.
        #pragma unroll
        for (int rr = 0; rr < 2; ++rr) {
            const int r = g * 2 + rr;
            const int* ip = &sidx[r * KNEI];
            float4 acc = {0.f, 0.f, 0.f, 0.f};
            #pragma unroll
            for (int k = 0; k < KNEI; ++k) {
                float4 v = raw4[(size_t)ip[k] * 32 + c];
                acc.x += v.x; acc.y += v.y; acc.z += v.z; acc.w += v.w;
            }
            ushort4 b;
            b.x = f2bf(acc.x * 0.0625f); b.y = f2bf(acc.y * 0.0625f);
            b.z = f2bf(acc.z * 0.0625f); b.w = f2bf(acc.w * 0.0625f);
            *(ushort4*)&sA[r * A_LD + c * 4] = b;   // 8B store, 8B aligned
        }
        __syncthreads();

        // MFMA: wave wv computes n-tiles n0=wv*32 and n0+16 for all 16 rows.
        // A-frag: lane holds A[m=lane&15][k=qd*8 + j]; B-frag: B[k][n=lane&15] from sWt rows.
        f32x4 acc0 = {0.f, 0.f, 0.f, 0.f}, acc1 = {0.f, 0.f, 0.f, 0.f};
        const int n0 = wv * 32 + ln, n1 = n0 + 16;
        #pragma unroll
        for (int kt = 0; kt < 4; ++kt) {
            const int k0 = kt * 32 + qd * 8;
            bf16x8 a  = *(const bf16x8*)&sA[ln * A_LD + k0];
            bf16x8 b0 = *(const bf16x8*)&sWt[n0 * WT_LD + k0];
            bf16x8 b1 = *(const bf16x8*)&sWt[n1 * WT_LD + k0];
            acc0 = __builtin_amdgcn_mfma_f32_16x16x32_bf16(a, b0, acc0, 0, 0, 0);
            acc1 = __builtin_amdgcn_mfma_f32_16x16x32_bf16(a, b1, acc1, 0, 0, 0);
        }

        // Epilogue: C/D layout col=lane&15, row=qd*4+reg. Write x, accumulate stats.
        #pragma unroll
        for (int ri = 0; ri < 4; ++ri) {
            const int row = i0 + qd * 4 + ri;
            float v0 = acc0[ri], v1 = acc1[ri];
            out[row * FEAT + n0] = v0;
            out[row * FEAT + n1] = v1;
            s1a += v0; s2a += v0 * v0;
            s1b += v1; s2b += v1 * v1;
        }
    }

    // Reduce quads within wave (lanes l, l+16, l+32, l+48 share feature n)
    s1a += __shfl_down(s1a, 32); s1a += __shfl_down(s1a, 16);
    s2a += __shfl_down(s2a, 32); s2a += __shfl_down(s2a, 16);
    s1b += __shfl_down(s1b, 32); s1b += __shfl_down(s1b, 16);
    s2b += __shfl_down(s2b, 32); s2b += __shfl_down(s2b, 16);
    if ((lane >> 4) == 0) {
        const int n0 = wv * 32 + ln, n1 = n0 + 16;
        atomicAdd(&gstats[n0], s1a);
        atomicAdd(&gstats[FEAT + n0], s2a);
        atomicAdd(&gstats[n1], s1b);
        atomicAdd(&gstats[FEAT + n1], s2b);
    }
}

__global__ __launch_bounds__(256) void enc_bn(
    float* __restrict__ out, const float* __restrict__ gstats,
    const float* __restrict__ gamma, const float* __restrict__ beta)
{
    __shared__ float sScale[FEAT], sShift[FEAT];
    const int t = threadIdx.x;
    if (t < FEAT) {
        float s1 = gstats[t], s2 = gstats[FEAT + t];
        float mean = s1 * (1.0f / NB);
        float var = s2 * (1.0f / NB) - mean * mean;
        float sc = gamma[t] * rsqrtf(var + 1e-5f);
        sScale[t] = sc;
        sShift[t] = beta[t] - mean * sc;
    }
    __syncthreads();

    const int total4 = NB * FEAT / 4;   // 1.6M float4
    float4* o4 = (float4*)out;
    for (int e = blockIdx.x * blockDim.x + t; e < total4; e += gridDim.x * blockDim.x) {
        const int f4 = (e & 31) * 4;
        float4 v = o4[e];
        float4 r;
        float y;
        y = v.x * sScale[f4 + 0] + sShift[f4 + 0]; r.x = (y >= 0.f) ? y : 0.01f * y;
        y = v.y * sScale[f4 + 1] + sShift[f4 + 1]; r.y = (y >= 0.f) ? y : 0.01f * y;
        y = v.z * sScale[f4 + 2] + sShift[f4 + 2]; r.z = (y >= 0.f) ? y : 0.01f * y;
        y = v.w * sScale[f4 + 3] + sShift[f4 + 3]; r.w = (y >= 0.f) ? y : 0.01f * y;
        o4[e] = r;
    }
}

extern "C" void kernel_launch(void* const* d_in, const int* in_sizes, int n_in,
                              void* d_out, int out_size, void* d_ws, size_t ws_size,
                              hipStream_t stream) {
    const float* raw   = (const float*)d_in[0];
    const float* W     = (const float*)d_in[1];
    const float* gamma = (const float*)d_in[2];
    const float* beta  = (const float*)d_in[3];
    const int*   idx   = (const int*)d_in[4];
    float* out = (float*)d_out;
    float* gstats = (float*)d_ws;   // [0:128] sum, [128:256] sumsq

    hipMemsetAsync(gstats, 0, 2 * FEAT * sizeof(float), stream);
    enc_gemm<<<1024, 256, 0, stream>>>(raw, W, idx, out, gstats);
    enc_bn<<<1024, 256, 0, stream>>>(out, gstats, gamma, beta);
}